// Round 3
// baseline (71.606 us; speedup 1.0000x reference)
//
#include <hip/hip_runtime.h>

// K_attention_MH: per-token Gaussian head-mixing.
//   G = X X^T (16x16x64)  via 2x mfma_f32_16x16x32_f16  (A-frag == B-frag)
//   dist2(h,g) = G_hh + G_gg - 2 G_hg ;  K = exp(-dist2*sigma)  (symmetric)
//   Y = X + K @ X  via mfma_f32_16x16x16f16 with C-init = X (residual free)
// 256 threads (4 waves) per token; each wave redundantly computes K, then
// owns one 16-dim output chunk. Coalesced float4 load AND store (store goes
// through a ys LDS transpose). 4096 blocks -> 8 waves/SIMD resident.

#define NH 16
#define HD 64
#define CC 1024
#define L 68  // LDS row stride in floats (pad 4: keeps 16B align, 2-way max)

typedef float    f32x4 __attribute__((ext_vector_type(4)));
typedef _Float16 f16x4 __attribute__((ext_vector_type(4)));
typedef _Float16 f16x8 __attribute__((ext_vector_type(8)));

__global__ __launch_bounds__(256) void K_attention_MH_kernel(
    const float* __restrict__ x,
    const float* __restrict__ r_sigma,
    float* __restrict__ y) {
  __shared__ __align__(16) float xs[NH * L];   // 4.35 KB
  __shared__ __align__(16) float ys[NH * L];   // 4.35 KB
  __shared__ __align__(16) float dg[4][NH];    // per-wave diag of G

  const int tid  = threadIdx.x;
  const int wid  = tid >> 6;
  const int lane = tid & 63;
  const int q    = lane >> 4;   // 0..3
  const int col  = lane & 15;   // 0..15
  const int tok  = blockIdx.x;

  const float* xp = x + (size_t)tok * CC;
  float*       yp = y + (size_t)tok * CC;
  const float sigma = r_sigma[0];

  // ---- stage: one float4 per thread, coalesced ----
  const float4 v = reinterpret_cast<const float4*>(xp)[tid];
  const int h  = tid >> 4;          // head row this thread's float4 lands in
  const int d0 = (tid & 15) * 4;    // dim offset
  *reinterpret_cast<float4*>(&xs[h * L + d0]) = v;
  __syncthreads();

  // ---- Gram: G = X X^T, computed redundantly by every wave ----
  // Lane l holds X[col][8q+j] -> identical fragment serves as A and B.
  f32x4 g = {0.f, 0.f, 0.f, 0.f};
#pragma unroll
  for (int kc = 0; kc < 2; ++kc) {
    const float4 a0 = *reinterpret_cast<const float4*>(&xs[col * L + 8 * q + 32 * kc]);
    const float4 a1 = *reinterpret_cast<const float4*>(&xs[col * L + 8 * q + 32 * kc + 4]);
    f16x8 af;
    af[0] = (_Float16)a0.x; af[1] = (_Float16)a0.y;
    af[2] = (_Float16)a0.z; af[3] = (_Float16)a0.w;
    af[4] = (_Float16)a1.x; af[5] = (_Float16)a1.y;
    af[6] = (_Float16)a1.z; af[7] = (_Float16)a1.w;
    g = __builtin_amdgcn_mfma_f32_16x16x32_f16(af, af, g, 0, 0, 0);
  }
  // g[r] = G[4q+r][col]

  // ---- diagonal exchange via tiny per-wave LDS table ----
  if ((col >> 2) == q) {
    const int rsel = col & 3;
    dg[wid][col] = (rsel == 0) ? g[0] : (rsel == 1) ? g[1]
                 : (rsel == 2) ? g[2] : g[3];
  }
  __builtin_amdgcn_wave_barrier();
  const float dgc = dg[wid][col];                                     // G[col][col]
  const f32x4 dh  = *reinterpret_cast<const f32x4*>(&dg[wid][4 * q]); // G[4q+r][..]

  // ---- K fragment: ka[r] = K[4q+r][col]; symmetry => valid A-frag ----
  f16x4 ka;
#pragma unroll
  for (int r = 0; r < 4; ++r) {
    const float d2 = dh[r] + dgc - 2.0f * g[r];
    ka[r] = (_Float16)__expf(-sigma * d2);
  }

  // ---- PV: wave wid owns d-chunk [16*wid, 16*wid+16). C-init = X ----
  const int dc = 16 * wid;
  f16x4 bfr;
  f32x4 acc;
#pragma unroll
  for (int j = 0; j < 4; ++j) {
    const float xb = xs[(4 * q + j) * L + dc + col];  // X[4q+j][dc+col]
    bfr[j] = (_Float16)xb;
    acc[j] = xb;                                      // residual via C
  }
  acc = __builtin_amdgcn_mfma_f32_16x16x16f16(ka, bfr, acc, 0, 0, 0);

  // D[4q+r][dc+col] -> ys, then coalesced float4 store
#pragma unroll
  for (int r = 0; r < 4; ++r)
    ys[(4 * q + r) * L + dc + col] = acc[r];
  __syncthreads();

  const float4 o = *reinterpret_cast<const float4*>(&ys[h * L + d0]);
  reinterpret_cast<float4*>(yp)[tid] = o;
}

extern "C" void kernel_launch(void* const* d_in, const int* in_sizes, int n_in,
                              void* d_out, int out_size, void* d_ws, size_t ws_size,
                              hipStream_t stream) {
  const float* x = (const float*)d_in[0];
  const float* r_sigma = (const float*)d_in[1];
  float* out = (float*)d_out;
  const int ntok = in_sizes[0] / CC;  // B*T = 4096
  K_attention_MH_kernel<<<ntok, 256, 0, stream>>>(x, r_sigma, out);
}

// Round 5
// 69.471 us; speedup vs baseline: 1.0307x; 1.0307x over previous
//
#include <hip/hip_runtime.h>

// K_attention_MH: per-token Gaussian head-mixing, wave-per-token MFMA version.
//   G = X X^T (16x16x64)  via 2x mfma_f32_16x16x32_f16  (A-frag == B-frag)
//   dist2(h,g) = G_hh + G_gg - 2 G_hg ;  K = exp(-dist2*sigma)  (symmetric)
//   Y = X + K @ X  via 4x mfma_f32_16x16x16f16, C-init = X (residual free)
// One wave per token, private LDS partition, NO __syncthreads (wave-lockstep
// LDS is in-order). Gram computed once per token. Coalesced float4 load AND
// store; PV results written back into xs in-place for the store transpose.

#define NH 16
#define HD 64
#define CC 1024
#define L 68  // LDS row stride (floats): 16B-aligned rows, <=2-way bank alias

typedef float    f32x4 __attribute__((ext_vector_type(4)));
typedef _Float16 f16x4 __attribute__((ext_vector_type(4)));
typedef _Float16 f16x8 __attribute__((ext_vector_type(8)));

__global__ __launch_bounds__(256, 2) void K_attention_MH_kernel(
    const float* __restrict__ x,
    const float* __restrict__ r_sigma,
    float* __restrict__ y,
    int ntok) {
  __shared__ __align__(16) float xs[4][NH * L];  // 4 x 4.35 KB, per-wave
  __shared__ __align__(16) float dg[4][NH];      // per-wave Gram diagonal

  const int wid  = threadIdx.x >> 6;
  const int lane = threadIdx.x & 63;
  const int tok  = blockIdx.x * 4 + wid;
  if (tok >= ntok) return;  // wave-uniform exit; no block barriers anywhere

  const float* xp = x + (size_t)tok * CC;
  float*       yp = y + (size_t)tok * CC;
  float* xw = xs[wid];
  float* dw = dg[wid];

  const int q   = lane >> 4;   // 0..3
  const int col = lane & 15;   // 0..15

  // ---- issue the 4 coalesced float4 loads first (cover HBM latency) ----
  float4 v[4];
#pragma unroll
  for (int i = 0; i < 4; ++i)
    v[i] = reinterpret_cast<const float4*>(xp)[lane + 64 * i];

  const float nsig = -r_sigma[0];

  // ---- stage into LDS rows: float p0 = 4*(lane+64i) -> h = q+4i, d0 = 4*col
#pragma unroll
  for (int i = 0; i < 4; ++i)
    *reinterpret_cast<float4*>(&xw[(q + 4 * i) * L + 4 * col]) = v[i];
  __builtin_amdgcn_wave_barrier();

  // ---- Gram: G = X X^T. Lane l holds X[col][32kc+8q+j] -> A-frag == B-frag
  f32x4 g = {0.f, 0.f, 0.f, 0.f};
#pragma unroll
  for (int kc = 0; kc < 2; ++kc) {
    const float4 a0 = *reinterpret_cast<const float4*>(&xw[col * L + 8 * q + 32 * kc]);
    const float4 a1 = *reinterpret_cast<const float4*>(&xw[col * L + 8 * q + 32 * kc + 4]);
    f16x8 af;
    af[0] = (_Float16)a0.x; af[1] = (_Float16)a0.y;
    af[2] = (_Float16)a0.z; af[3] = (_Float16)a0.w;
    af[4] = (_Float16)a1.x; af[5] = (_Float16)a1.y;
    af[6] = (_Float16)a1.z; af[7] = (_Float16)a1.w;
    g = __builtin_amdgcn_mfma_f32_16x16x32_f16(af, af, g, 0, 0, 0);
  }
  // g[r] = G[4q+r][col]

  // ---- diagonal exchange (16 lanes write, broadcast reads) ----
  if ((col >> 2) == q) {
    const int rsel = col & 3;
    dw[col] = (rsel == 0) ? g[0] : (rsel == 1) ? g[1]
            : (rsel == 2) ? g[2] : g[3];
  }
  __builtin_amdgcn_wave_barrier();
  const float dgc = dw[col];                                    // G[col][col]
  const f32x4 dh  = *reinterpret_cast<const f32x4*>(&dw[4 * q]);// G[4q+r][4q+r]

  // ---- K fragment: ka[j] = K[4q+j][col] == K[col][4q+j] (symmetry) ----
  f16x4 ka;
#pragma unroll
  for (int r = 0; r < 4; ++r) {
    const float d2 = dh[r] + dgc - 2.0f * g[r];
    ka[r] = (_Float16)__expf(nsig * d2);
  }

  // ---- PV per 16-dim chunk; C-init = X gives residual; write back in-place
  // (within a chunk: all lanes' ds_reads feed the MFMA, which precedes the
  //  ds_writes in wave-lockstep program order -> no race; chunks disjoint)
#pragma unroll
  for (int c = 0; c < 4; ++c) {
    f16x4 bfr;
    f32x4 acc;
#pragma unroll
    for (int j = 0; j < 4; ++j) {
      const float xb = xw[(4 * q + j) * L + 16 * c + col];  // X[4q+j][16c+col]
      bfr[j] = (_Float16)xb;
      acc[j] = xb;                                          // residual via C
    }
    acc = __builtin_amdgcn_mfma_f32_16x16x16f16(ka, bfr, acc, 0, 0, 0);
#pragma unroll
    for (int r = 0; r < 4; ++r)
      xw[(4 * q + r) * L + 16 * c + col] = acc[r];          // Y in-place
  }
  __builtin_amdgcn_wave_barrier();

  // ---- coalesced store: same mapping as the load ----
#pragma unroll
  for (int i = 0; i < 4; ++i) {
    const float4 o = *reinterpret_cast<const float4*>(&xw[(q + 4 * i) * L + 4 * col]);
    reinterpret_cast<float4*>(yp)[lane + 64 * i] = o;
  }
}

extern "C" void kernel_launch(void* const* d_in, const int* in_sizes, int n_in,
                              void* d_out, int out_size, void* d_ws, size_t ws_size,
                              hipStream_t stream) {
  const float* x = (const float*)d_in[0];
  const float* r_sigma = (const float*)d_in[1];
  float* out = (float*)d_out;
  const int ntok = in_sizes[0] / CC;            // B*T = 4096
  const int blocks = (ntok + 3) / 4;            // 4 tokens (waves) per block
  K_attention_MH_kernel<<<blocks, 256, 0, stream>>>(x, r_sigma, out, ntok);
}